// Round 4
// baseline (161.133 us; speedup 1.0000x reference)
//
#include <hip/hip_runtime.h>
#include <hip/hip_bf16.h>

#define BN 8192
#define DK 512
#define PN 4096
#define GY 8
#define PPB 512            // protos per slice (16 classes)
#define CH 32              // protos per chunk == one class (sorted)
#define NCH 16             // chunks per slice
#define STRIDE 520         // row stride in elems (1040 B) -> 2-way-free banks
#define SENT (-1.0e30f)
#define L2E 1.4426950408889634f
#define LN2 0.6931471805599453f

typedef __bf16 bf16x8 __attribute__((ext_vector_type(8)));
typedef float f32x4 __attribute__((ext_vector_type(4)));

__device__ __forceinline__ float ex2(float x) { return __builtin_amdgcn_exp2f(x); }

__device__ __forceinline__ void gl_lds16(const void* g, void* l) {
    __builtin_amdgcn_global_load_lds(
        (const __attribute__((address_space(1))) void*)g,
        (__attribute__((address_space(3))) void*)l, 16, 0, 0);
}

// ---------------------------------------------------------------------------
// K1: bf16 casts of protos (class-sorted) AND features; p_sq*log2e (sorted);
// zero the combine counters. One wave per row, 8 elems/lane.
// ---------------------------------------------------------------------------
__global__ __launch_bounds__(256) void k_prep(const float* __restrict__ feat,
                                              const float* __restrict__ proto,
                                              __bf16* __restrict__ fB,
                                              __bf16* __restrict__ pB,
                                              float* __restrict__ p_sq,
                                              int* __restrict__ cnt) {
    int r  = blockIdx.x * 4 + (threadIdx.x >> 6);
    int ln = threadIdx.x & 63;
    if (blockIdx.x == 0 && threadIdx.x < 64) cnt[threadIdx.x] = 0;
    if (r < PN) {
        const float* src = proto + (size_t)r * DK;
        float4 a = *(const float4*)(src + ln * 8);
        float4 b = *(const float4*)(src + ln * 8 + 4);
        float s = a.x * a.x + a.y * a.y + a.z * a.z + a.w * a.w
                + b.x * b.x + b.y * b.y + b.z * b.z + b.w * b.w;
#pragma unroll
        for (int m = 1; m < 64; m <<= 1) s += __shfl_xor(s, m, 64);
        int sidx = (r & 127) * 32 + (r >> 7);   // class-sorted row
        bf16x8 c;
        c[0] = (__bf16)a.x; c[1] = (__bf16)a.y; c[2] = (__bf16)a.z; c[3] = (__bf16)a.w;
        c[4] = (__bf16)b.x; c[5] = (__bf16)b.y; c[6] = (__bf16)b.z; c[7] = (__bf16)b.w;
        *(bf16x8*)(pB + (size_t)sidx * DK + ln * 8) = c;
        if (ln == 0) p_sq[sidx] = s * L2E;
    } else {
        int rf = r - PN;
        const float* src = feat + (size_t)rf * DK;
        float4 a = *(const float4*)(src + ln * 8);
        float4 b = *(const float4*)(src + ln * 8 + 4);
        bf16x8 c;
        c[0] = (__bf16)a.x; c[1] = (__bf16)a.y; c[2] = (__bf16)a.z; c[3] = (__bf16)a.w;
        c[4] = (__bf16)b.x; c[5] = (__bf16)b.y; c[6] = (__bf16)b.z; c[7] = (__bf16)b.w;
        *(bf16x8*)(fB + (size_t)rf * DK + ln * 8) = c;
    }
}

// ---------------------------------------------------------------------------
// K2: fused GEMM + online logsumexp (log2 domain) + last-block combine.
// Wave owns 32 rows; afrag loaded DIRECTLY from global bf16 (no A staging).
// B: 32-proto chunks (== one class), double-buffered via global_load_lds.
// Numerator: single conditional set (class == chunk, sorted layout).
// ---------------------------------------------------------------------------
__global__ __launch_bounds__(256, 2) void k_main(
        const __bf16* __restrict__ fB,
        const __bf16* __restrict__ pB,
        const float* __restrict__ p_sq,    // sorted, pre-scaled by log2(e)
        const int* __restrict__ label,
        float4* __restrict__ part,
        int* __restrict__ cnt,
        float* __restrict__ out) {

    __shared__ __bf16 sM[2 * CH * STRIDE];   // 66,560 B
    __shared__ float  sPsq[PPB];             // 2 KB
    __shared__ int    sLast;

    const int t    = threadIdx.x;
    const int w    = t >> 6;
    const int l    = t & 63;
    const int ln   = l & 15;
    const int quad = l >> 4;
    const int bx   = blockIdx.x;
    const int gy   = blockIdx.y;
    const int rw   = bx * 128 + w * 32;
    const int p0   = gy * PPB;

    // ---- issue chunk-0 prefetch into buf0 FIRST ----
    {
        const __bf16* g = pB + (size_t)(p0 + w * 8) * DK + l * 8;
        __bf16* lp = sM + (w * 8) * STRIDE;
#pragma unroll
        for (int j = 0; j < 8; ++j)
            gl_lds16(g + j * DK, lp + j * STRIDE);
    }

    // ---- afrag directly from global bf16 (overlaps the prefetch) ----
    bf16x8 afrag[2][16];
    {
        const __bf16* fb = fB + (size_t)(rw + ln) * DK + quad * 8;
#pragma unroll
        for (int mf = 0; mf < 2; ++mf)
#pragma unroll
            for (int ks = 0; ks < 16; ++ks)
                afrag[mf][ks] = *(const bf16x8*)(fb + (size_t)mf * 16 * DK + ks * 32);
    }

    int lab[2][4];
#pragma unroll
    for (int mf = 0; mf < 2; ++mf)
#pragma unroll
        for (int r = 0; r < 4; ++r)
            lab[mf][r] = label[rw + mf * 16 + quad * 4 + r];

    sPsq[t]       = p_sq[p0 + t];
    sPsq[t + 256] = p_sq[p0 + t + 256];
    __syncthreads();   // chunk0 + psq ready

    float Md[2][4], Sd[2][4], Mn[2][4], Sn[2][4];
#pragma unroll
    for (int mf = 0; mf < 2; ++mf)
#pragma unroll
        for (int r = 0; r < 4; ++r) {
            Md[mf][r] = SENT; Sd[mf][r] = 0.f;
            Mn[mf][r] = SENT; Sn[mf][r] = 0.f;
        }

#pragma unroll 1
    for (int nt = 0; nt < NCH; ++nt) {
        if (nt + 1 < NCH) {
            const __bf16* g = pB + (size_t)(p0 + (nt + 1) * CH + w * 8) * DK + l * 8;
            __bf16* lp = sM + (((nt + 1) & 1) * CH + w * 8) * STRIDE;
#pragma unroll
            for (int j = 0; j < 8; ++j)
                gl_lds16(g + j * DK, lp + j * STRIDE);
        }

        const __bf16* sB = sM + (nt & 1) * CH * STRIDE;

        f32x4 acc[2][2];
#pragma unroll
        for (int mf = 0; mf < 2; ++mf)
#pragma unroll
            for (int nf = 0; nf < 2; ++nf)
                acc[mf][nf] = (f32x4){0.f, 0.f, 0.f, 0.f};

#pragma unroll
        for (int ks = 0; ks < 16; ++ks) {
            bf16x8 b0 = *(const bf16x8*)(sB + ln * STRIDE + ks * 32 + quad * 8);
            bf16x8 b1 = *(const bf16x8*)(sB + (16 + ln) * STRIDE + ks * 32 + quad * 8);
            acc[0][0] = __builtin_amdgcn_mfma_f32_16x16x32_bf16(afrag[0][ks], b0, acc[0][0], 0, 0, 0);
            acc[0][1] = __builtin_amdgcn_mfma_f32_16x16x32_bf16(afrag[0][ks], b1, acc[0][1], 0, 0, 0);
            acc[1][0] = __builtin_amdgcn_mfma_f32_16x16x32_bf16(afrag[1][ks], b0, acc[1][0], 0, 0, 0);
            acc[1][1] = __builtin_amdgcn_mfma_f32_16x16x32_bf16(afrag[1][ks], b1, acc[1][1], 0, 0, 0);
        }

        float nps0 = -sPsq[nt * 32 + ln];
        float nps1 = -sPsq[nt * 32 + 16 + ln];
        const int cls = gy * 16 + nt;

        float z[2][2][4];
#pragma unroll
        for (int mf = 0; mf < 2; ++mf)
#pragma unroll
            for (int r = 0; r < 4; ++r) {
                z[mf][0][r] = fmaf(acc[mf][0][r], 2.0f * L2E, nps0);
                z[mf][1][r] = fmaf(acc[mf][1][r], 2.0f * L2E, nps1);
            }

        // batched denominator update
#pragma unroll
        for (int mf = 0; mf < 2; ++mf)
#pragma unroll
            for (int r = 0; r < 4; ++r) {
                float z0 = z[mf][0][r], z1 = z[mf][1][r];
                float nm = fmaxf(Md[mf][r], fmaxf(z0, z1));
                float e  = ex2(z0 - nm) + ex2(z1 - nm);
                Sd[mf][r] = fmaf(Sd[mf][r], ex2(Md[mf][r] - nm), e);
                Md[mf][r] = nm;
            }

        // numerator: single-shot (class-sorted => exactly one chunk per row)
        int anyhit = 0;
#pragma unroll
        for (int mf = 0; mf < 2; ++mf)
#pragma unroll
            for (int r = 0; r < 4; ++r)
                anyhit |= (cls == lab[mf][r]);
        if (__any(anyhit)) {
#pragma unroll
            for (int mf = 0; mf < 2; ++mf)
#pragma unroll
                for (int r = 0; r < 4; ++r) {
                    bool hit = (cls == lab[mf][r]);
                    float z0 = z[mf][0][r], z1 = z[mf][1][r];
                    float nm = fmaxf(z0, z1);
                    float sn = ex2(z0 - nm) + ex2(z1 - nm);
                    Mn[mf][r] = hit ? nm : Mn[mf][r];
                    Sn[mf][r] = hit ? sn : Sn[mf][r];
                }
        }
        __syncthreads();
    }

    // ---- merge 16 lanes per quad-group, write partials ----
#pragma unroll
    for (int mf = 0; mf < 2; ++mf)
#pragma unroll
        for (int r = 0; r < 4; ++r) {
            float md = Md[mf][r], sd = Sd[mf][r];
            float mn = Mn[mf][r], sn = Sn[mf][r];
#pragma unroll
            for (int m = 1; m < 16; m <<= 1) {
                float omd = __shfl_xor(md, m, 64);
                float osd = __shfl_xor(sd, m, 64);
                float omn = __shfl_xor(mn, m, 64);
                float osn = __shfl_xor(sn, m, 64);
                float nm = fmaxf(md, omd);
                sd = sd * ex2(md - nm) + osd * ex2(omd - nm);
                md = nm;
                nm = fmaxf(mn, omn);
                sn = sn * ex2(mn - nm) + osn * ex2(omn - nm);
                mn = nm;
            }
            if (ln == 0) {
                int row = rw + mf * 16 + quad * 4 + r;
                part[row * GY + gy] = make_float4(md, sd, mn, sn);
            }
        }

    // ---- last gy-block for this bx combines and writes the final loss ----
    __threadfence();
    if (t == 0) sLast = (atomicAdd(&cnt[bx], 1) == GY - 1);
    __syncthreads();
    if (sLast && t < 128) {
        __threadfence();
        int row = bx * 128 + t;
        float md = SENT, sd = 0.f, mn = SENT, sn = 0.f;
#pragma unroll
        for (int q = 0; q < GY; ++q) {
            float4 v = part[row * GY + q];
            float nm = fmaxf(md, v.x);
            sd = sd * ex2(md - nm) + v.y * ex2(v.x - nm);
            md = nm;
            nm = fmaxf(mn, v.z);
            sn = sn * ex2(mn - nm) + v.w * ex2(v.z - nm);
            mn = nm;
        }
        out[row] = ((md + __builtin_amdgcn_logf(sd)) - (mn + __builtin_amdgcn_logf(sn))) * LN2;
    }
}

extern "C" void kernel_launch(void* const* d_in, const int* in_sizes, int n_in,
                              void* d_out, int out_size, void* d_ws, size_t ws_size,
                              hipStream_t stream) {
    const float* feat   = (const float*)d_in[0];
    const int*   label  = (const int*)d_in[1];
    const float* proto  = (const float*)d_in[2];
    float*       out    = (float*)d_out;

    char* w = (char*)d_ws;
    __bf16* fB    = (__bf16*)(w);                  // 8192*512*2 = 8,388,608
    __bf16* pB    = (__bf16*)(w + 8388608);        // 4096*512*2 = 4,194,304
    float*  p_sq  = (float*)(w + 12582912);        // 16,384
    float4* part  = (float4*)(w + 12599296);       // 1,048,576
    int*    cnt   = (int*)(w + 13647872);          // 256

    hipLaunchKernelGGL(k_prep, dim3((PN + BN) / 4), dim3(256), 0, stream,
                       feat, proto, fB, pB, p_sq, cnt);
    hipLaunchKernelGGL(k_main, dim3(64, GY), dim3(256), 0, stream,
                       fB, pB, p_sq, label, part, cnt, out);
}

// Round 5
// 118.880 us; speedup vs baseline: 1.3554x; 1.3554x over previous
//
#include <hip/hip_runtime.h>
#include <hip/hip_bf16.h>

#define BN 8192
#define DK 512
#define PN 4096
#define GY 8
#define PPB 512            // protos per slice (16 classes)
#define CH 32              // protos per chunk == one class (sorted)
#define NCH 16             // chunks per slice
#define STRIDE 520         // row stride in elems (1040 B) -> 2-way-free banks
#define SENT (-1.0e30f)
#define L2E 1.4426950408889634f
#define LN2 0.6931471805599453f

typedef __bf16 bf16x8 __attribute__((ext_vector_type(8)));
typedef float f32x4 __attribute__((ext_vector_type(4)));

__device__ __forceinline__ float ex2(float x) { return __builtin_amdgcn_exp2f(x); }

__device__ __forceinline__ void gl_lds16(const void* g, void* l) {
    __builtin_amdgcn_global_load_lds(
        (const __attribute__((address_space(1))) void*)g,
        (__attribute__((address_space(3))) void*)l, 16, 0, 0);
}

// ---------------------------------------------------------------------------
// K1: bf16 casts of protos (class-sorted) AND features; p_sq*log2e (sorted).
// One wave per row, 8 elems/lane.
// ---------------------------------------------------------------------------
__global__ __launch_bounds__(256) void k_prep(const float* __restrict__ feat,
                                              const float* __restrict__ proto,
                                              __bf16* __restrict__ fB,
                                              __bf16* __restrict__ pB,
                                              float* __restrict__ p_sq) {
    int r  = blockIdx.x * 4 + (threadIdx.x >> 6);
    int ln = threadIdx.x & 63;
    if (r < PN) {
        const float* src = proto + (size_t)r * DK;
        float4 a = *(const float4*)(src + ln * 8);
        float4 b = *(const float4*)(src + ln * 8 + 4);
        float s = a.x * a.x + a.y * a.y + a.z * a.z + a.w * a.w
                + b.x * b.x + b.y * b.y + b.z * b.z + b.w * b.w;
#pragma unroll
        for (int m = 1; m < 64; m <<= 1) s += __shfl_xor(s, m, 64);
        int sidx = (r & 127) * 32 + (r >> 7);   // class-sorted row
        bf16x8 c;
        c[0] = (__bf16)a.x; c[1] = (__bf16)a.y; c[2] = (__bf16)a.z; c[3] = (__bf16)a.w;
        c[4] = (__bf16)b.x; c[5] = (__bf16)b.y; c[6] = (__bf16)b.z; c[7] = (__bf16)b.w;
        *(bf16x8*)(pB + (size_t)sidx * DK + ln * 8) = c;
        if (ln == 0) p_sq[sidx] = s * L2E;
    } else {
        int rf = r - PN;
        const float* src = feat + (size_t)rf * DK;
        float4 a = *(const float4*)(src + ln * 8);
        float4 b = *(const float4*)(src + ln * 8 + 4);
        bf16x8 c;
        c[0] = (__bf16)a.x; c[1] = (__bf16)a.y; c[2] = (__bf16)a.z; c[3] = (__bf16)a.w;
        c[4] = (__bf16)b.x; c[5] = (__bf16)b.y; c[6] = (__bf16)b.z; c[7] = (__bf16)b.w;
        *(bf16x8*)(fB + (size_t)rf * DK + ln * 8) = c;
    }
}

// ---------------------------------------------------------------------------
// K2: fused GEMM + online logsumexp (log2 domain).
// Wave owns 32 rows; afrag loaded DIRECTLY from global bf16 (no A staging,
// overlaps chunk-0 prefetch). B: 32-proto chunks (== one class), double-
// buffered via global_load_lds. Numerator: single conditional set.
// NO device-scope fences/atomics mid-grid: a per-block release fence
// (round 4) L2-thrashed co-resident blocks (+43 us).
// ---------------------------------------------------------------------------
__global__ __launch_bounds__(256, 2) void k_main(
        const __bf16* __restrict__ fB,
        const __bf16* __restrict__ pB,
        const float* __restrict__ p_sq,    // sorted, pre-scaled by log2(e)
        const int* __restrict__ label,
        float4* __restrict__ part) {

    __shared__ __bf16 sM[2 * CH * STRIDE];   // 66,560 B
    __shared__ float  sPsq[PPB];             // 2 KB

    const int t    = threadIdx.x;
    const int w    = t >> 6;
    const int l    = t & 63;
    const int ln   = l & 15;
    const int quad = l >> 4;
    const int bx   = blockIdx.x;
    const int gy   = blockIdx.y;
    const int rw   = bx * 128 + w * 32;
    const int p0   = gy * PPB;

    // ---- issue chunk-0 prefetch into buf0 FIRST ----
    {
        const __bf16* g = pB + (size_t)(p0 + w * 8) * DK + l * 8;
        __bf16* lp = sM + (w * 8) * STRIDE;
#pragma unroll
        for (int j = 0; j < 8; ++j)
            gl_lds16(g + j * DK, lp + j * STRIDE);
    }

    // ---- afrag directly from global bf16 (overlaps the prefetch) ----
    bf16x8 afrag[2][16];
    {
        const __bf16* fb = fB + (size_t)(rw + ln) * DK + quad * 8;
#pragma unroll
        for (int mf = 0; mf < 2; ++mf)
#pragma unroll
            for (int ks = 0; ks < 16; ++ks)
                afrag[mf][ks] = *(const bf16x8*)(fb + (size_t)mf * 16 * DK + ks * 32);
    }

    int lab[2][4];
#pragma unroll
    for (int mf = 0; mf < 2; ++mf)
#pragma unroll
        for (int r = 0; r < 4; ++r)
            lab[mf][r] = label[rw + mf * 16 + quad * 4 + r];

    sPsq[t]       = p_sq[p0 + t];
    sPsq[t + 256] = p_sq[p0 + t + 256];
    __syncthreads();   // chunk0 + psq ready

    float Md[2][4], Sd[2][4], Mn[2][4], Sn[2][4];
#pragma unroll
    for (int mf = 0; mf < 2; ++mf)
#pragma unroll
        for (int r = 0; r < 4; ++r) {
            Md[mf][r] = SENT; Sd[mf][r] = 0.f;
            Mn[mf][r] = SENT; Sn[mf][r] = 0.f;
        }

#pragma unroll 1
    for (int nt = 0; nt < NCH; ++nt) {
        if (nt + 1 < NCH) {
            const __bf16* g = pB + (size_t)(p0 + (nt + 1) * CH + w * 8) * DK + l * 8;
            __bf16* lp = sM + (((nt + 1) & 1) * CH + w * 8) * STRIDE;
#pragma unroll
            for (int j = 0; j < 8; ++j)
                gl_lds16(g + j * DK, lp + j * STRIDE);
        }

        const __bf16* sB = sM + (nt & 1) * CH * STRIDE;

        f32x4 acc[2][2];
#pragma unroll
        for (int mf = 0; mf < 2; ++mf)
#pragma unroll
            for (int nf = 0; nf < 2; ++nf)
                acc[mf][nf] = (f32x4){0.f, 0.f, 0.f, 0.f};

#pragma unroll
        for (int ks = 0; ks < 16; ++ks) {
            bf16x8 b0 = *(const bf16x8*)(sB + ln * STRIDE + ks * 32 + quad * 8);
            bf16x8 b1 = *(const bf16x8*)(sB + (16 + ln) * STRIDE + ks * 32 + quad * 8);
            acc[0][0] = __builtin_amdgcn_mfma_f32_16x16x32_bf16(afrag[0][ks], b0, acc[0][0], 0, 0, 0);
            acc[0][1] = __builtin_amdgcn_mfma_f32_16x16x32_bf16(afrag[0][ks], b1, acc[0][1], 0, 0, 0);
            acc[1][0] = __builtin_amdgcn_mfma_f32_16x16x32_bf16(afrag[1][ks], b0, acc[1][0], 0, 0, 0);
            acc[1][1] = __builtin_amdgcn_mfma_f32_16x16x32_bf16(afrag[1][ks], b1, acc[1][1], 0, 0, 0);
        }

        float nps0 = -sPsq[nt * 32 + ln];
        float nps1 = -sPsq[nt * 32 + 16 + ln];
        const int cls = gy * 16 + nt;

        float z[2][2][4];
#pragma unroll
        for (int mf = 0; mf < 2; ++mf)
#pragma unroll
            for (int r = 0; r < 4; ++r) {
                z[mf][0][r] = fmaf(acc[mf][0][r], 2.0f * L2E, nps0);
                z[mf][1][r] = fmaf(acc[mf][1][r], 2.0f * L2E, nps1);
            }

        // batched denominator update: one rescale per (mf,r) per chunk
#pragma unroll
        for (int mf = 0; mf < 2; ++mf)
#pragma unroll
            for (int r = 0; r < 4; ++r) {
                float z0 = z[mf][0][r], z1 = z[mf][1][r];
                float nm = fmaxf(Md[mf][r], fmaxf(z0, z1));
                float e  = ex2(z0 - nm) + ex2(z1 - nm);
                Sd[mf][r] = fmaf(Sd[mf][r], ex2(Md[mf][r] - nm), e);
                Md[mf][r] = nm;
            }

        // numerator: single-shot (class-sorted => exactly one chunk per row)
        int anyhit = 0;
#pragma unroll
        for (int mf = 0; mf < 2; ++mf)
#pragma unroll
            for (int r = 0; r < 4; ++r)
                anyhit |= (cls == lab[mf][r]);
        if (__any(anyhit)) {
#pragma unroll
            for (int mf = 0; mf < 2; ++mf)
#pragma unroll
                for (int r = 0; r < 4; ++r) {
                    bool hit = (cls == lab[mf][r]);
                    float z0 = z[mf][0][r], z1 = z[mf][1][r];
                    float nm = fmaxf(z0, z1);
                    float sn = ex2(z0 - nm) + ex2(z1 - nm);
                    Mn[mf][r] = hit ? nm : Mn[mf][r];
                    Sn[mf][r] = hit ? sn : Sn[mf][r];
                }
        }
        __syncthreads();
    }

    // ---- merge 16 lanes per quad-group, write partials ----
#pragma unroll
    for (int mf = 0; mf < 2; ++mf)
#pragma unroll
        for (int r = 0; r < 4; ++r) {
            float md = Md[mf][r], sd = Sd[mf][r];
            float mn = Mn[mf][r], sn = Sn[mf][r];
#pragma unroll
            for (int m = 1; m < 16; m <<= 1) {
                float omd = __shfl_xor(md, m, 64);
                float osd = __shfl_xor(sd, m, 64);
                float omn = __shfl_xor(mn, m, 64);
                float osn = __shfl_xor(sn, m, 64);
                float nm = fmaxf(md, omd);
                sd = sd * ex2(md - nm) + osd * ex2(omd - nm);
                md = nm;
                nm = fmaxf(mn, omn);
                sn = sn * ex2(mn - nm) + osn * ex2(omn - nm);
                mn = nm;
            }
            if (ln == 0) {
                int row = rw + mf * 16 + quad * 4 + r;
                part[row * GY + gy] = make_float4(md, sd, mn, sn);
            }
        }
}

// ---------------------------------------------------------------------------
// K3: merge the GY partials per row (log2 domain), final loss in nats.
// Kernel boundary = the cheap coherence point (no mid-grid fences).
// ---------------------------------------------------------------------------
__global__ __launch_bounds__(256) void k_comb(const float4* __restrict__ part,
                                              float* __restrict__ out) {
    int row = blockIdx.x * 256 + threadIdx.x;
    float md = SENT, sd = 0.f, mn = SENT, sn = 0.f;
#pragma unroll
    for (int q = 0; q < GY; ++q) {
        float4 v = part[row * GY + q];
        float nm = fmaxf(md, v.x);
        sd = sd * ex2(md - nm) + v.y * ex2(v.x - nm);
        md = nm;
        nm = fmaxf(mn, v.z);
        sn = sn * ex2(mn - nm) + v.w * ex2(v.z - nm);
        mn = nm;
    }
    out[row] = ((md + __builtin_amdgcn_logf(sd)) - (mn + __builtin_amdgcn_logf(sn))) * LN2;
}

extern "C" void kernel_launch(void* const* d_in, const int* in_sizes, int n_in,
                              void* d_out, int out_size, void* d_ws, size_t ws_size,
                              hipStream_t stream) {
    const float* feat   = (const float*)d_in[0];
    const int*   label  = (const int*)d_in[1];
    const float* proto  = (const float*)d_in[2];
    float*       out    = (float*)d_out;

    char* w = (char*)d_ws;
    __bf16* fB    = (__bf16*)(w);                  // 8192*512*2 = 8,388,608
    __bf16* pB    = (__bf16*)(w + 8388608);        // 4096*512*2 = 4,194,304
    float*  p_sq  = (float*)(w + 12582912);        // 16,384
    float4* part  = (float4*)(w + 12599296);       // 1,048,576

    hipLaunchKernelGGL(k_prep, dim3((PN + BN) / 4), dim3(256), 0, stream,
                       feat, proto, fB, pB, p_sq);
    hipLaunchKernelGGL(k_main, dim3(64, GY), dim3(256), 0, stream,
                       fB, pB, p_sq, label, part);
    hipLaunchKernelGGL(k_comb, dim3(BN / 256), dim3(256), 0, stream,
                       part, out);
}